// Round 1
// 951.767 us; speedup vs baseline: 1.8099x; 1.8099x over previous
//
#include <hip/hip_runtime.h>
#include <hip/hip_bf16.h>

#define LSEQ   2048
#define NHEAD  16
#define NCHUNK 32
#define WKV_NB 32
#define SSD_NB 1024   // NBATCH*NCHUNK*NHEAD

// workspace layout (floats)
#define WS_CS 0u          // chunk states -> (after scan) entering states, (sid,p,n)
#define WS_YD 4194304u    // Y_diag f32, (b,l,h,p) == output layout
#define WS_CA 8388608u    // per-chunk inclusive cumsum of A, (sid,64)

__device__ __forceinline__ float rl(float x, int l) {
    return __int_as_float(__builtin_amdgcn_readlane(__float_as_int(x), l));
}

// ---------------------------------------------------------------------------
// Fused kernel: blocks [0,32) = WKV (4 waves, column-split state),
//               blocks [32,1056) = SSD intra-chunk (256 threads)
// ---------------------------------------------------------------------------
__global__ __launch_bounds__(256)
void k_fused(const float* __restrict__ X, const float* __restrict__ A,
             const float* __restrict__ Bm, const float* __restrict__ Cm,
             const float* __restrict__ rg, const float* __restrict__ kg,
             const float* __restrict__ vg, const float* __restrict__ wg,
             const float* __restrict__ bg, float* __restrict__ ws,
             float* __restrict__ out)
{
    __shared__ float Bs[64][68];
    __shared__ float CsGL[64][68];
    __shared__ float Xs[64][64];
    __shared__ float cA[64], decL[64];

    const int t = threadIdx.x;

    if (blockIdx.x < WKV_NB) {
        // ===== WKV: 4 waves per (b,h); lane = state row i, wave = 16 columns =====
        const int lane = t & 63;
        const int w4   = t >> 6;          // wave id 0..3
        const int jb   = w4 << 4;         // first owned column

        float* sp = &Bs[0][0];            // [2][4][64] cross-wave dot partials
        float* yp = &Xs[0][0];            // [2][8][4][64] y partials (tile parity)

        const int bh = blockIdx.x;
        const int b  = bh >> 4, h = bh & 15;
        const size_t base = (size_t)bh * LSEQ * 64 + lane;
        const float* pr = rg + base;
        const float* pk = kg + base;
        const float* pv = vg + base;
        const float* pw = wg + base;
        const float* pb = bg + base;
        float* pout = out + ((size_t)b * LSEQ * NHEAD + h) * 64 + lane;

        float st[16];                     // S[lane][jb..jb+15] / alpha
        #pragma unroll
        for (int c = 0; c < 16; c++) st[c] = 0.f;
        float alpha = 1.f, ialpha = 1.f;

        // STATIC double-buffer register sets (no runtime indexing!)
        float R0[8], K0[8], V0[8], W0[8], B0[8];
        float R1[8], K1[8], V1[8], W1[8], B1[8];

        auto pref = [&](float (&R)[8], float (&K)[8], float (&V)[8],
                        float (&W)[8], float (&Bb)[8], int tb) {
            #pragma unroll
            for (int m = 0; m < 8; m++) {
                size_t o = (size_t)(tb + m) * 64;
                R[m] = pr[o]; K[m] = pk[o]; V[m] = pv[o]; W[m] = pw[o]; Bb[m] = pb[o];
            }
        };

        auto proc = [&](float (&R)[8], float (&K)[8], float (&V)[8],
                        float (&W)[8], float (&Bb)[8], int tb) {
            float* ypb = yp + (((tb >> 3) & 1) << 11);   // tile-parity buffer
            float iW[8];
            #pragma unroll
            for (int m = 0; m < 8; m++) iW[m] = __builtin_amdgcn_rcpf(W[m]);
            float raA = 0.f, raB = 0.f;

            #pragma unroll
            for (int m = 0; m < 8; m++) {
                // k[j] for own columns is wave-uniform -> SGPRs via readlane
                float ks[16];
                #pragma unroll
                for (int c = 0; c < 16; c++) ks[c] = rl(K[m], jb + c);

                // partial dot over own 16 columns
                float a0 = 0.f, a1 = 0.f, a2 = 0.f, a3 = 0.f;
                #pragma unroll
                for (int c = 0; c < 16; c += 4) {
                    a0 += st[c + 0] * ks[c + 0]; a1 += st[c + 1] * ks[c + 1];
                    a2 += st[c + 2] * ks[c + 2]; a3 += st[c + 3] * ks[c + 3];
                }
                float* spb = sp + ((m & 1) << 8);        // step-parity buffer
                spb[(w4 << 6) + lane] = (a0 + a1) + (a2 + a3);

                // raw barrier: drain LDS only, keep global prefetch in flight
                asm volatile("s_waitcnt lgkmcnt(0)" ::: "memory");
                __builtin_amdgcn_s_barrier();
                asm volatile("" ::: "memory");

                float s01 = spb[lane] + spb[64 + lane];
                float s23 = spb[128 + lane] + spb[192 + lane];
                float delta = V[m] - alpha * (s01 + s23);

                alpha  *= W[m];
                ialpha *= iW[m];
                const float coef = (Bb[m] * K[m]) * ialpha;   // S = alpha*st invariant
                float rv = R[m] * alpha;
                if ((m >> 1) == w4) { if (m & 1) raB = rv; else raA = rv; }

                // delta[j] for own columns (identical in every wave) -> SGPRs
                float ds[16];
                #pragma unroll
                for (int c = 0; c < 16; c++) ds[c] = rl(delta, jb + c);

                // fused state update + y partial over own columns
                float y0 = 0.f, y1 = 0.f, y2 = 0.f, y3 = 0.f;
                #pragma unroll
                for (int c = 0; c < 16; c += 4) {
                    st[c + 0] += coef * ds[c + 0]; y0 += st[c + 0] * ks[c + 0];
                    st[c + 1] += coef * ds[c + 1]; y1 += st[c + 1] * ks[c + 1];
                    st[c + 2] += coef * ds[c + 2]; y2 += st[c + 2] * ks[c + 2];
                    st[c + 3] += coef * ds[c + 3]; y3 += st[c + 3] * ks[c + 3];
                }
                ypb[(m << 8) + (w4 << 6) + lane] = (y0 + y1) + (y2 + y3);
            }

            // fold alpha back into st (alpha >= 0.9^8 = 0.43)
            #pragma unroll
            for (int c = 0; c < 16; c++) st[c] *= alpha;
            alpha = 1.f; ialpha = 1.f;

            // publish y partials, then wave w4 emits timesteps tb+2w4, tb+2w4+1
            asm volatile("s_waitcnt lgkmcnt(0)" ::: "memory");
            __builtin_amdgcn_s_barrier();
            asm volatile("" ::: "memory");

            const float* q0 = ypb + ((w4 * 2) << 8) + lane;
            const float* q1 = ypb + ((w4 * 2 + 1) << 8) + lane;
            float ya = ((q0[0] + q0[64]) + (q0[128] + q0[192])) * raA;
            float yb = ((q1[0] + q1[64]) + (q1[128] + q1[192])) * raB;
            pout[(size_t)(tb + w4 * 2)     * (NHEAD * 64)] = ya;
            pout[(size_t)(tb + w4 * 2 + 1) * (NHEAD * 64)] = yb;
        };

        pref(R0, K0, V0, W0, B0, 0);
        for (int t0 = 0; t0 < LSEQ; t0 += 16) {
            pref(R1, K1, V1, W1, B1, t0 + 8);       // t0+8 <= 2040 always valid
            proc(R0, K0, V0, W0, B0, t0);
            if (t0 + 16 < LSEQ) pref(R0, K0, V0, W0, B0, t0 + 16);
            proc(R1, K1, V1, W1, B1, t0 + 8);
        }
        return;
    }

    // ================= SSD intra-chunk =================
    const int sid = blockIdx.x - WKV_NB;
    const int b = sid >> 9;
    const int c = (sid >> 4) & 31;
    const int h = sid & 15;
    const size_t rowbase = ((size_t)(b * LSEQ + c * 64) * NHEAD + h) * 64;
    const int rstride = NHEAD * 64;   // 1024

    #pragma unroll
    for (int i = 0; i < 4; i++) {
        int fl = t + 256 * i; int row = fl >> 4; int c4 = fl & 15;
        size_t go = rowbase + (size_t)row * rstride;
        float4 xv = ((const float4*)(X  + go))[c4];
        float4 bv = ((const float4*)(Bm + go))[c4];
        float4 cv = ((const float4*)(Cm + go))[c4];
        *(float4*)&Xs[row][c4 * 4]   = xv;
        *(float4*)&Bs[row][c4 * 4]   = bv;
        *(float4*)&CsGL[row][c4 * 4] = cv;
    }
    if (t < 64) {
        float a = A[(size_t)(b * LSEQ + c * 64 + t) * NHEAD + h];
        float s = a;
        #pragma unroll
        for (int off = 1; off < 64; off <<= 1) {
            float nv = __shfl_up(s, off, 64);
            if (t >= off) s += nv;
        }
        cA[t] = s;
        ws[WS_CA + (size_t)sid * 64 + t] = s;
        float tot = __shfl(s, 63, 64);
        decL[t] = expf(tot - s);
    }
    __syncthreads();

    const int l = t >> 2;
    const int q = t & 3;

    // G[l][s] = <C_l, B_s> * exp(cA[l]-cA[s]) for s<=l else 0   (s = q + 4*si)
    float g[16];
    {
        float acc[16];
        #pragma unroll
        for (int si = 0; si < 16; si++) acc[si] = 0.f;
        #pragma unroll
        for (int n4 = 0; n4 < 16; n4++) {
            float4 cv = *(const float4*)&CsGL[l][n4 * 4];
            #pragma unroll
            for (int si = 0; si < 16; si++) {
                float4 bv = *(const float4*)&Bs[q + 4 * si][n4 * 4];
                acc[si] += cv.x * bv.x + cv.y * bv.y + cv.z * bv.z + cv.w * bv.w;
            }
        }
        float cl = cA[l];
        #pragma unroll
        for (int si = 0; si < 16; si++) {
            int s = q + 4 * si;
            g[si] = (s <= l) ? acc[si] * expf(cl - cA[s]) : 0.f;
        }
    }
    __syncthreads();
    #pragma unroll
    for (int si = 0; si < 16; si++) CsGL[l][q + 4 * si] = g[si];
    __syncthreads();

    // Y_diag[l][p] = sum_s GL[l][s] * X[s][p]
    {
        const int pb = q * 16;
        float4 acc[4];
        #pragma unroll
        for (int i = 0; i < 4; i++) acc[i] = make_float4(0.f, 0.f, 0.f, 0.f);
        for (int s = 0; s < 64; s++) {
            float gv = CsGL[l][s];
            #pragma unroll
            for (int i = 0; i < 4; i++) {
                float4 xv = *(const float4*)&Xs[s][pb + 4 * i];
                acc[i].x += gv * xv.x; acc[i].y += gv * xv.y;
                acc[i].z += gv * xv.z; acc[i].w += gv * xv.w;
            }
        }
        size_t o = rowbase + (size_t)l * rstride + pb;
        float* yd = ws + WS_YD;
        #pragma unroll
        for (int i = 0; i < 4; i++) ((float4*)(yd + o))[i] = acc[i];
    }

    // chunk_states[p][n] = sum_l decL[l] * X[l][p] * B[l][n]
    {
        const int p  = l;
        const int nb = q * 16;
        float4 acc[4];
        #pragma unroll
        for (int i = 0; i < 4; i++) acc[i] = make_float4(0.f, 0.f, 0.f, 0.f);
        for (int l2 = 0; l2 < 64; l2++) {
            float cf = decL[l2] * Xs[l2][p];
            #pragma unroll
            for (int i = 0; i < 4; i++) {
                float4 bv = *(const float4*)&Bs[l2][nb + 4 * i];
                acc[i].x += cf * bv.x; acc[i].y += cf * bv.y;
                acc[i].z += cf * bv.z; acc[i].w += cf * bv.w;
            }
        }
        float* cs = ws + WS_CS + (size_t)sid * 4096 + (size_t)p * 64 + nb;
        #pragma unroll
        for (int i = 0; i < 4; i++) ((float4*)cs)[i] = acc[i];
    }
}

// ---------------------------------------------------------------------------
// K2: inter-chunk scan per (b,h): overwrite cs_c with state ENTERING chunk c
// ---------------------------------------------------------------------------
__global__ __launch_bounds__(256)
void k_scan(float* __restrict__ ws)
{
    const int t = threadIdx.x;
    const int b = blockIdx.x >> 4;
    const int h = blockIdx.x & 15;
    float prev[16];
    #pragma unroll
    for (int qq = 0; qq < 16; qq++) prev[qq] = 0.f;
    for (int c = 0; c < NCHUNK; c++) {
        const int sid = b * 512 + c * 16 + h;
        float dec = expf(ws[WS_CA + (size_t)sid * 64 + 63]);
        float* cs = ws + WS_CS + (size_t)sid * 4096;
        float tmp[16];
        #pragma unroll
        for (int qq = 0; qq < 16; qq++) tmp[qq] = cs[t + 256 * qq];
        #pragma unroll
        for (int qq = 0; qq < 16; qq++) cs[t + 256 * qq] = prev[qq];
        #pragma unroll
        for (int qq = 0; qq < 16; qq++) prev[qq] = prev[qq] * dec + tmp[qq];
    }
}

// ---------------------------------------------------------------------------
// K3: out = Y_diag + exp(cumA[l]) * C_l . state^T + out(=wkv)    (all f32)
// ---------------------------------------------------------------------------
__global__ __launch_bounds__(256)
void k_yoff(const float* __restrict__ Cm, const float* __restrict__ ws,
            float* __restrict__ out)
{
    __shared__ float Cs[64][68];
    __shared__ float ST[64][68];   // ST[n][p] = state[p][n]
    __shared__ float dout[64];
    const int t = threadIdx.x;
    const int sid = blockIdx.x;
    const int b = sid >> 9;
    const int c = (sid >> 4) & 31;
    const int h = sid & 15;
    const size_t rowbase = ((size_t)(b * LSEQ + c * 64) * NHEAD + h) * 64;
    const int rstride = NHEAD * 64;

    #pragma unroll
    for (int i = 0; i < 4; i++) {
        int fl = t + 256 * i; int row = fl >> 4; int c4 = fl & 15;
        float4 cv = ((const float4*)(Cm + rowbase + (size_t)row * rstride))[c4];
        *(float4*)&Cs[row][c4 * 4] = cv;
        float4 sv = ((const float4*)(ws + WS_CS + (size_t)sid * 4096 + (size_t)row * 64))[c4];
        ST[c4 * 4 + 0][row] = sv.x;
        ST[c4 * 4 + 1][row] = sv.y;
        ST[c4 * 4 + 2][row] = sv.z;
        ST[c4 * 4 + 3][row] = sv.w;
    }
    if (t < 64) dout[t] = expf(ws[WS_CA + (size_t)sid * 64 + t]);
    __syncthreads();

    const int l  = t >> 2;
    const int pb = (t & 3) * 16;
    float4 acc[4];
    #pragma unroll
    for (int i = 0; i < 4; i++) acc[i] = make_float4(0.f, 0.f, 0.f, 0.f);
    for (int n = 0; n < 64; n++) {
        float cv = Cs[l][n];
        #pragma unroll
        for (int i = 0; i < 4; i++) {
            float4 sv = *(const float4*)&ST[n][pb + 4 * i];
            acc[i].x += cv * sv.x; acc[i].y += cv * sv.y;
            acc[i].z += cv * sv.z; acc[i].w += cv * sv.w;
        }
    }
    const float sc = dout[l];
    const size_t o = rowbase + (size_t)l * rstride + pb;
    #pragma unroll
    for (int i = 0; i < 4; i++) {
        float4 yd = ((const float4*)(ws + WS_YD + o))[i];
        float4 yw = ((const float4*)(out + o))[i];
        float4 res;
        res.x = yd.x + sc * acc[i].x + yw.x;
        res.y = yd.y + sc * acc[i].y + yw.y;
        res.z = yd.z + sc * acc[i].z + yw.z;
        res.w = yd.w + sc * acc[i].w + yw.w;
        ((float4*)(out + o))[i] = res;
    }
}

extern "C" void kernel_launch(void* const* d_in, const int* in_sizes, int n_in,
                              void* d_out, int out_size, void* d_ws, size_t ws_size,
                              hipStream_t stream)
{
    const float* X  = (const float*)d_in[0];
    const float* A  = (const float*)d_in[1];
    const float* Bm = (const float*)d_in[2];
    const float* Cm = (const float*)d_in[3];
    const float* r  = (const float*)d_in[4];
    const float* k  = (const float*)d_in[5];
    const float* v  = (const float*)d_in[6];
    const float* w  = (const float*)d_in[7];
    const float* bo = (const float*)d_in[8];
    float* ws = (float*)d_ws;
    float* out = (float*)d_out;

    hipLaunchKernelGGL(k_fused, dim3(WKV_NB + SSD_NB), dim3(256), 0, stream,
                       X, A, Bm, Cm, r, k, v, w, bo, ws, out);
    hipLaunchKernelGGL(k_scan, dim3(32),     dim3(256), 0, stream, ws);
    hipLaunchKernelGGL(k_yoff, dim3(SSD_NB), dim3(256), 0, stream, Cm, ws, out);
}